// Round 11
// baseline (127.831 us; speedup 1.0000x reference)
//
#include <hip/hip_runtime.h>
#include <math.h>

#define EDIM 128
#define NHEAD 16
#define HDIM 8
#define SEQ 2048
#define BATCH 4
#define NROW (BATCH*SEQ)            // 8192
// -scale*log2(e): folded into Q at projection time so sigmoid = rcp(1+exp2(dot))
#define QNEG (-0.35355339059327373f * 1.4426950408889634f)

#if __has_builtin(__builtin_amdgcn_exp2f)
#define EXP2F(x) __builtin_amdgcn_exp2f(x)
#else
#define EXP2F(x) exp2f(x)
#endif
#define RCPF(x) __builtin_amdgcn_rcpf(x)

typedef __attribute__((ext_vector_type(8))) short short8v;
typedef __attribute__((ext_vector_type(4))) short short4v;
typedef __attribute__((ext_vector_type(4))) float float4v;

union U16x8 { uint4 u; short8v s; };
union U16x4 { uint2 u; short4v s; };

#if __has_builtin(__builtin_amdgcn_mfma_f32_16x16x16bf16_1k)
#define MFMA_PV(a,b,c) __builtin_amdgcn_mfma_f32_16x16x16bf16_1k(a,b,c,0,0,0)
#else
static __device__ __forceinline__ float4v mfma_pv_asm(short4v a, short4v b, float4v c) {
  float4v d;
  asm("v_mfma_f32_16x16x16_bf16 %0, %1, %2, %3" : "=v"(d) : "v"(a), "v"(b), "v"(c));
  return d;
}
#define MFMA_PV(a,b,c) mfma_pv_asm(a,b,c)
#endif

// pack two floats to bf16x2, round-to-nearest-even-ish (values finite)
__device__ __forceinline__ unsigned pk_bf16(float a, float b) {
  unsigned ua = __float_as_uint(a), ub = __float_as_uint(b);
  unsigned lo = (ua + 0x7fffu + ((ua >> 16) & 1u)) >> 16;
  unsigned hi = (ub + 0x7fffu + ((ub >> 16) & 1u)) & 0xffff0000u;
  return lo | hi;
}

// A-frags from swizzled LDS: A lane l: A[m=l&15][k=(l>>4)*8+j]
__device__ __forceinline__
void afrags(const unsigned short* xs, int lq, int qd, short8v a[4])
{
  #pragma unroll
  for (int kk = 0; kk < 4; ++kk) {
    const unsigned addr =
        (unsigned)(lq * 256 + kk * 64 + qd * 16) ^ (unsigned)((lq & 7) << 4);
    a[kk] = *(const short8v*)((const char*)xs + addr);
  }
}

// ---------------------------------------------------------------------------
// 32-row x 128-col MFMA projection block, W staged per-block into LDS.
// (unchanged from R10 — projections are byte-identical this round)
// ---------------------------------------------------------------------------
template<int MODE>
__device__ __forceinline__
void proj32(const float* __restrict__ X, const float* __restrict__ W,
            const float* __restrict__ bias, void* __restrict__ out,
            int row0, int tid,
            unsigned short* wlds, unsigned short* xs, unsigned short* bnc)
{
  // ---- stage W: 2 threads per row, 64 cols (16 float4) each, coalesced ----
  {
    const int n = tid >> 1, h = (tid & 1) * 64;
    const float4* src = (const float4*)(W + (size_t)n * EDIM + h);
    const unsigned xr = (unsigned)((n & 7) << 4);
    #pragma unroll
    for (int j = 0; j < 8; ++j) {
      const float4 f0 = src[2 * j], f1 = src[2 * j + 1];
      const uint4 v = make_uint4(pk_bf16(f0.x, f0.y), pk_bf16(f0.z, f0.w),
                                 pk_bf16(f1.x, f1.y), pk_bf16(f1.z, f1.w));
      *(uint4*)((char*)wlds + ((unsigned)(n * 256 + h * 2 + j * 16) ^ xr)) = v;
    }
  }
  // ---- stage X: 8 threads per row (32 rows), 16 cols each ----
  {
    const int r = tid >> 3, c = tid & 7;
    const float4* src = (const float4*)(X + (size_t)(row0 + r) * EDIM + c * 16);
    const unsigned xr = (unsigned)((r & 7) << 4);
    const float4 f0 = src[0], f1 = src[1], f2 = src[2], f3 = src[3];
    const uint4 v0 = make_uint4(pk_bf16(f0.x, f0.y), pk_bf16(f0.z, f0.w),
                                pk_bf16(f1.x, f1.y), pk_bf16(f1.z, f1.w));
    const uint4 v1 = make_uint4(pk_bf16(f2.x, f2.y), pk_bf16(f2.z, f2.w),
                                pk_bf16(f3.x, f3.y), pk_bf16(f3.z, f3.w));
    *(uint4*)((char*)xs + ((unsigned)(r * 256 + c * 32) ^ xr)) = v0;
    *(uint4*)((char*)xs + ((unsigned)(r * 256 + c * 32 + 16) ^ xr)) = v1;
  }
  __syncthreads();

  const int lane = tid & 63, wv = tid >> 6;
  const int lq = lane & 15, qd = lane >> 4;
  const int n0 = wv * 32;

  // ---- B-frags once per wave (two 16-col tiles) ----
  short8v b0[4], b1[4];
  #pragma unroll
  for (int kk = 0; kk < 4; ++kk) {
    const unsigned ad = (unsigned)((n0 + lq) * 256 + kk * 64 + qd * 16)
                      ^ (unsigned)((lq & 7) << 4);
    b0[kk] = *(const short8v*)((const char*)wlds + ad);
    b1[kk] = *(const short8v*)((const char*)wlds + ad + 4096);  // +16 rows
  }

  const int nA = n0 + lq, nB = nA + 16;
  const float bzA = bias[nA], bzB = bias[nB];
  const int b_ = row0 >> 11;

  #pragma unroll
  for (int rt = 0; rt < 2; ++rt) {
    const int rowt = row0 + rt * 16;
    short8v a[4];
    afrags(xs + rt * 2048, lq, qd, a);

    float4v D0 = {0.f, 0.f, 0.f, 0.f}, D1 = {0.f, 0.f, 0.f, 0.f};
    #pragma unroll
    for (int kk = 0; kk < 4; ++kk) {
      D0 = __builtin_amdgcn_mfma_f32_16x16x32_bf16(a[kk], b0[kk], D0, 0, 0, 0);
      D1 = __builtin_amdgcn_mfma_f32_16x16x32_bf16(a[kk], b1[kk], D1, 0, 0, 0);
    }

    if (MODE == 3) {
      float* of = (float*)out + (size_t)(rowt + qd * 4) * EDIM + nA;
      #pragma unroll
      for (int r = 0; r < 4; ++r) {
        of[r * EDIM]      = D0[r] + bzA;
        of[r * EDIM + 16] = D1[r] + bzB;
      }
      continue;
    }

    const int srel = rowt & (SEQ - 1);

    if (MODE == 2) {
      // Vt[bh][tg][d][si]: row-tile = one 16-s tile; si = qd*4 + r.
      const int tg = srel >> 4;
      unsigned short* oU = (unsigned short*)out;
      {
        const int bh = b_ * NHEAD + (nA >> 3), dv = nA & 7;
        uint2 p;
        p.x = pk_bf16(D0[0] + bzA, D0[1] + bzA);
        p.y = pk_bf16(D0[2] + bzA, D0[3] + bzA);
        *(uint2*)(oU + (size_t)bh * (SEQ * HDIM) + tg * 128 + dv * 16 + qd * 4) = p;
      }
      {
        const int bh = b_ * NHEAD + (nB >> 3), dv = nB & 7;
        uint2 p;
        p.x = pk_bf16(D1[0] + bzB, D1[1] + bzB);
        p.y = pk_bf16(D1[2] + bzB, D1[3] + bzB);
        *(uint2*)(oU + (size_t)bh * (SEQ * HDIM) + tg * 128 + dv * 16 + qd * 4) = p;
      }
      continue;
    }

    // MODE 0/1: bounce both 16x16 tiles through padded LDS ([16][20] u16),
    // then contiguous 256B uint4 stores (one [bh][s][8] row per lane).
    #pragma unroll
    for (int r = 0; r < 4; ++r) {
      float vA = D0[r] + bzA, vB = D1[r] + bzB;
      if (MODE == 0) { vA *= QNEG; vB *= QNEG; }
      const int m = qd * 4 + r;
      bnc[m * 20 + lq]       = (unsigned short)pk_bf16(vA, 0.f);
      bnc[320 + m * 20 + lq] = (unsigned short)pk_bf16(vB, 0.f);
    }
    __syncthreads();                              // LDS write->read order

    const int mm   = lane & 15;
    const int half = (lane >> 4) & 1;
    const int tile = lane >> 5;
    const unsigned short* sp = bnc + tile * 320 + mm * 20 + half * 8;
    const uint2 w0 = *(const uint2*)sp;
    const uint2 w1 = *(const uint2*)(sp + 4);
    const int bh = b_ * NHEAD + wv * 4 + tile * 2 + half;
    unsigned short* dp = (unsigned short*)out + ((size_t)bh * SEQ + srel + mm) * 8;
    *(uint4*)dp = make_uint4(w0.x, w0.y, w1.x, w1.y);
    __syncthreads();                              // bnc reuse guard (next rt)
  }
}

__global__ __launch_bounds__(256)
void qkv_kernel(const float* __restrict__ X,
                const float* __restrict__ Wq, const float* __restrict__ Wk,
                const float* __restrict__ Wv,
                const float* __restrict__ bq, const float* __restrict__ bk,
                const float* __restrict__ bv,
                unsigned* __restrict__ qb, unsigned* __restrict__ kb,
                unsigned* __restrict__ vb)
{
  __shared__ __align__(16) unsigned short wlds[16384];   // 32 KB
  __shared__ __align__(16) unsigned short xs[4096];      // 8 KB
  __shared__ __align__(16) unsigned short bnc[4 * 640];  // 5 KB
  const int tid = threadIdx.x;
  const int row0 = blockIdx.x * 32;
  unsigned short* myb = bnc + (tid >> 6) * 640;
  const int m = blockIdx.y;
  if (m == 0)      proj32<0>(X, Wq, bq, (void*)qb, row0, tid, wlds, xs, myb);
  else if (m == 1) proj32<1>(X, Wk, bk, (void*)kb, row0, tid, wlds, xs, myb);
  else             proj32<2>(X, Wv, bv, (void*)vb, row0, tid, wlds, xs, myb);
}

__global__ __launch_bounds__(256)
void oproj_kernel(const float* __restrict__ A, const float* __restrict__ Wo,
                  const float* __restrict__ bo, float* __restrict__ out)
{
  __shared__ __align__(16) unsigned short wlds[16384];   // 32 KB
  __shared__ __align__(16) unsigned short xs[4096];      // 8 KB
  proj32<3>(A, Wo, bo, (void*)out, blockIdx.x * 32, threadIdx.x, wlds, xs, nullptr);
}

// ---------------------------------------------------------------------------
// One 16q x 16k MFMA step — NEW: batched reciprocal (1 rcp per 4 sigmoids).
// With a_i = 1+2^min(st_i,30): 1/a_i = (prod of the other three)*rcp(prod).
// Clamp keeps product < 2^121 (finite, no inf*0 NaN path); rel err ~2^-21,
// far below the bf16 quantization of P. Cuts the trans-pipe cost of the
// sigmoid from {4 exp2 + 4 rcp} to {4 exp2 + 1 rcp} per step (attn measured
// at the trans floor: VALU busy 28us ~= 134M*(exp2+rcp) issue time).
// Packing kept as verified perm + 0x8000 round-half-up (NOT cvt_pk asm).
// ---------------------------------------------------------------------------
template<bool DIAG>
__device__ __forceinline__
float4v attn_step(short8v kf, short8v qf, short4v vf, float4v acc,
                  int laneq, int quad)
{
  const float4v z = {0.f, 0.f, 0.f, 0.f};
  float4v st = __builtin_amdgcn_mfma_f32_16x16x32_bf16(kf, qf, z, 0, 0, 0);
  const float a0 = 1.f + EXP2F(fminf(st[0], 30.f));
  const float a1 = 1.f + EXP2F(fminf(st[1], 30.f));
  const float a2 = 1.f + EXP2F(fminf(st[2], 30.f));
  const float a3 = 1.f + EXP2F(fminf(st[3], 30.f));
  const float ab = a0 * a1, cd = a2 * a3;
  const float r  = RCPF(ab * cd);                 // one trans op for 4 sigmoids
  const float rcd = r * cd, rab = r * ab;
  float p0 = a1 * rcd;                            // = 1/a0
  float p1 = a0 * rcd;                            // = 1/a1
  float p2 = a3 * rab;                            // = 1/a2
  float p3 = a2 * rab;                            // = 1/a3
  if (DIAG) {                                     // exact: sigma(-1e9)==0
    p0 = (4 * quad + 0 <= laneq) ? p0 : 0.f;
    p1 = (4 * quad + 1 <= laneq) ? p1 : 0.f;
    p2 = (4 * quad + 2 <= laneq) ? p2 : 0.f;
    p3 = (4 * quad + 3 <= laneq) ? p3 : 0.f;
  }
  unsigned rb[4];
  rb[0] = __float_as_uint(p0) + 0x8000u;          // round-half-up to bf16
  rb[1] = __float_as_uint(p1) + 0x8000u;
  rb[2] = __float_as_uint(p2) + 0x8000u;
  rb[3] = __float_as_uint(p3) + 0x8000u;
  U16x4 p;
  p.u.x = __builtin_amdgcn_perm(rb[1], rb[0], 0x07060302u);
  p.u.y = __builtin_amdgcn_perm(rb[3], rb[2], 0x07060302u);
  return MFMA_PV(p.s, vf, acc);                   // A = P[q][k], B = V[k][d]
}

// V-frag loader from tile-blocked Vt[bh][t][d][si]: ONE dwordx2 from a
// contiguous 256B tile block. lanes laneq==8 -> bf16 1.0 (denominator col).
__device__ __forceinline__
short4v load_vfrag(const unsigned short* __restrict__ Vtbh, int t,
                   int quad, int d, bool is8)
{
  const unsigned short* p = Vtbh + t * 128 + d * 16 + 4 * quad;
  const uint2 v = *(const uint2*)p;
  U16x4 vf;
  vf.u.x = is8 ? 0x3F803F80u : v.x;
  vf.u.y = is8 ? 0x3F803F80u : v.y;
  return vf.s;
}

// epilogue: den = acc col 8; normalize and store rows of tile T
__device__ __forceinline__
void epilogue(float4v acc, int T, int bh, int laneq, int quad,
              float* __restrict__ out)
{
  const int b_ = bh >> 4, h = bh & 15;
  const int pidx = (quad * 16 + 8) << 2;          // lane holding col 8
  #pragma unroll
  for (int r = 0; r < 4; ++r) {
    const float den = __int_as_float(
        __builtin_amdgcn_ds_bpermute(pidx, __float_as_int(acc[r])));
    const float val = acc[r] * RCPF(den);         // den > 0
    const int row = 16 * T + 4 * quad + r;
    if (laneq < 8)
      out[(size_t)(b_ * SEQ + row) * EDIM + h * HDIM + laneq] = val;
  }
}

// ---------------------------------------------------------------------------
// Causal sigmoid-attention v12: v11 schedule + batched-rcp sigmoid.
// blockIdx low 6 bits = bh -> XCD = bh%8 (L2 locality).
// ---------------------------------------------------------------------------
__global__ __launch_bounds__(128, 8)
void attn_kernel(const unsigned* __restrict__ Qb, const unsigned* __restrict__ Kb,
                 const unsigned* __restrict__ Vb, float* __restrict__ out)
{
  __shared__ float cmb[2][64][4];                 // 2 KB

  const int bh    = blockIdx.x & 63;
  const int g     = blockIdx.x >> 6;              // 0..63
  const int w     = threadIdx.x >> 6;
  const int lane  = threadIdx.x & 63;
  const int laneq = lane & 15;
  const int quad  = lane >> 4;
  const int L = g, H = 127 - g;
  const int mL = (L + 1) >> 1, mH = (H + 1) >> 1;
  const int d   = laneq & 7;
  const bool is8 = (laneq == 8);

  const uint4* Kg = (const uint4*)Kb + (size_t)bh * 2048;
  const uint4* Qg = (const uint4*)Qb + (size_t)bh * 2048;
  const unsigned short* Vtbh = (const unsigned short*)Vb + (size_t)bh * SEQ * HDIM;

  // Q B-frags: lanes<16 hold the 8-dim row in quad 0 (k=0..7); zero others
  U16x8 qfl, qfh;
  {
    const uint4 rl = Qg[16 * L + laneq];
    const uint4 rh = Qg[16 * H + laneq];
    qfl.u = (lane < 16) ? rl : make_uint4(0u, 0u, 0u, 0u);
    qfh.u = (lane < 16) ? rh : make_uint4(0u, 0u, 0u, 0u);
  }

  float4v accL = {0.f, 0.f, 0.f, 0.f};
  float4v accH = {0.f, 0.f, 0.f, 0.f};

  if (w == 0) {
    // k-tiles [0,mL) dual (L+H), [mL,mH) H-only; no diags; prefetch 1 deep
    U16x8 kf; kf.u = Kg[laneq];
    short4v vf = load_vfrag(Vtbh, 0, quad, d, is8);
    #pragma unroll 2
    for (int t = 0; t < mH; ++t) {
      U16x8 kn; kn.u = Kg[16 * (t + 1) + laneq];  // t+1 <= mH <= 64: in-bounds
      short4v vn = load_vfrag(Vtbh, t + 1, quad, d, is8);
      if (t < mL) accL = attn_step<false>(kf.s, qfl.s, vf, accL, laneq, quad);
      accH = attn_step<false>(kf.s, qfh.s, vf, accH, laneq, quad);
      kf = kn; vf = vn;
    }
  } else {
    // L segment: [mL, L], diag at L
    U16x8 kf; kf.u = Kg[16 * mL + laneq];
    short4v vf = load_vfrag(Vtbh, mL, quad, d, is8);
    #pragma unroll 2
    for (int t = mL; t < L; ++t) {
      U16x8 kn; kn.u = Kg[16 * (t + 1) + laneq];
      short4v vn = load_vfrag(Vtbh, t + 1, quad, d, is8);
      accL = attn_step<false>(kf.s, qfl.s, vf, accL, laneq, quad);
      kf = kn; vf = vn;
    }
    accL = attn_step<true>(kf.s, qfl.s, vf, accL, laneq, quad);
    // H segment: [mH, H], diag at H
    kf.u = Kg[16 * mH + laneq];
    vf = load_vfrag(Vtbh, mH, quad, d, is8);
    #pragma unroll 2
    for (int t = mH; t < H; ++t) {
      U16x8 kn; kn.u = Kg[16 * (t + 1) + laneq];  // t+1 <= H = 127: in-bounds
      short4v vn = load_vfrag(Vtbh, t + 1, quad, d, is8);
      accH = attn_step<false>(kf.s, qfh.s, vf, accH, laneq, quad);
      kf = kn; vf = vn;
    }
    accH = attn_step<true>(kf.s, qfh.s, vf, accH, laneq, quad);

    *(float4*)&cmb[0][lane][0] = make_float4(accL[0], accL[1], accL[2], accL[3]);
    *(float4*)&cmb[1][lane][0] = make_float4(accH[0], accH[1], accH[2], accH[3]);
  }
  __syncthreads();

  if (w == 0) {
    const float4 pL = *(const float4*)&cmb[0][lane][0];
    const float4 pH = *(const float4*)&cmb[1][lane][0];
    accL[0] += pL.x; accL[1] += pL.y; accL[2] += pL.z; accL[3] += pL.w;
    accH[0] += pH.x; accH[1] += pH.y; accH[2] += pH.z; accH[3] += pH.w;
    epilogue(accL, L, bh, laneq, quad, out);
    epilogue(accH, H, bh, laneq, quad, out);
  }
}

// ---------------------------------------------------------------------------
extern "C" void kernel_launch(void* const* d_in, const int* in_sizes, int n_in,
                              void* d_out, int out_size, void* d_ws, size_t ws_size,
                              hipStream_t stream)
{
  const float* x  = (const float*)d_in[0];
  const float* Wq = (const float*)d_in[1];
  const float* bq = (const float*)d_in[2];
  const float* Wk = (const float*)d_in[3];
  const float* bk = (const float*)d_in[4];
  const float* Wv = (const float*)d_in[5];
  const float* bv = (const float*)d_in[6];
  const float* Wo = (const float*)d_in[7];
  const float* bo = (const float*)d_in[8];

  float* ws = (float*)d_ws;
  // layout: (64K floats reserved) | attn 1048576 f | Qb, Kb, Vt 524288 dw each
  float*    attn = ws + 65536;
  unsigned* Qb   = (unsigned*)(ws + 65536 + 1048576);
  unsigned* Kb   = Qb + (size_t)524288;
  unsigned* Vb   = Kb + (size_t)524288;

  qkv_kernel<<<dim3(NROW / 32, 3), 256, 0, stream>>>(x, Wq, Wk, Wv, bq, bk, bv,
                                                     Qb, Kb, Vb);
  attn_kernel<<<dim3(4096), 128, 0, stream>>>(Qb, Kb, Vb, attn);
  oproj_kernel<<<dim3(NROW / 32), 256, 0, stream>>>(attn, Wo, bo, (float*)d_out);
}

// Round 12
// 121.710 us; speedup vs baseline: 1.0503x; 1.0503x over previous
//
#include <hip/hip_runtime.h>
#include <math.h>

#define EDIM 128
#define NHEAD 16
#define HDIM 8
#define SEQ 2048
#define BATCH 4
#define NROW (BATCH*SEQ)            // 8192
// -scale*log2(e): folded into Q at projection time so sigmoid = rcp(1+exp2(dot))
#define QNEG (-0.35355339059327373f * 1.4426950408889634f)

#if __has_builtin(__builtin_amdgcn_exp2f)
#define EXP2F(x) __builtin_amdgcn_exp2f(x)
#else
#define EXP2F(x) exp2f(x)
#endif
#define RCPF(x) __builtin_amdgcn_rcpf(x)

typedef __attribute__((ext_vector_type(8))) short short8v;
typedef __attribute__((ext_vector_type(4))) short short4v;
typedef __attribute__((ext_vector_type(4))) float float4v;

union U16x8 { uint4 u; short8v s; };
union U16x4 { uint2 u; short4v s; };

#if __has_builtin(__builtin_amdgcn_mfma_f32_16x16x16bf16_1k)
#define MFMA_PV(a,b,c) __builtin_amdgcn_mfma_f32_16x16x16bf16_1k(a,b,c,0,0,0)
#else
static __device__ __forceinline__ float4v mfma_pv_asm(short4v a, short4v b, float4v c) {
  float4v d;
  asm("v_mfma_f32_16x16x16_bf16 %0, %1, %2, %3" : "=v"(d) : "v"(a), "v"(b), "v"(c));
  return d;
}
#define MFMA_PV(a,b,c) mfma_pv_asm(a,b,c)
#endif

// pack two floats to bf16x2, round-to-nearest-even-ish (values finite)
__device__ __forceinline__ unsigned pk_bf16(float a, float b) {
  unsigned ua = __float_as_uint(a), ub = __float_as_uint(b);
  unsigned lo = (ua + 0x7fffu + ((ua >> 16) & 1u)) >> 16;
  unsigned hi = (ub + 0x7fffu + ((ub >> 16) & 1u)) & 0xffff0000u;
  return lo | hi;
}

// A-frags from swizzled LDS: A lane l: A[m=l&15][k=(l>>4)*8+j]
__device__ __forceinline__
void afrags(const unsigned short* xs, int lq, int qd, short8v a[4])
{
  #pragma unroll
  for (int kk = 0; kk < 4; ++kk) {
    const unsigned addr =
        (unsigned)(lq * 256 + kk * 64 + qd * 16) ^ (unsigned)((lq & 7) << 4);
    a[kk] = *(const short8v*)((const char*)xs + addr);
  }
}

// ---------------------------------------------------------------------------
// 32-row x 128-col MFMA projection block, W staged per-block into LDS.
// (unchanged from R10 — byte-identical outputs)
// ---------------------------------------------------------------------------
template<int MODE>
__device__ __forceinline__
void proj32(const float* __restrict__ X, const float* __restrict__ W,
            const float* __restrict__ bias, void* __restrict__ out,
            int row0, int tid,
            unsigned short* wlds, unsigned short* xs, unsigned short* bnc)
{
  // ---- stage W: 2 threads per row, 64 cols (16 float4) each, coalesced ----
  {
    const int n = tid >> 1, h = (tid & 1) * 64;
    const float4* src = (const float4*)(W + (size_t)n * EDIM + h);
    const unsigned xr = (unsigned)((n & 7) << 4);
    #pragma unroll
    for (int j = 0; j < 8; ++j) {
      const float4 f0 = src[2 * j], f1 = src[2 * j + 1];
      const uint4 v = make_uint4(pk_bf16(f0.x, f0.y), pk_bf16(f0.z, f0.w),
                                 pk_bf16(f1.x, f1.y), pk_bf16(f1.z, f1.w));
      *(uint4*)((char*)wlds + ((unsigned)(n * 256 + h * 2 + j * 16) ^ xr)) = v;
    }
  }
  // ---- stage X: 8 threads per row (32 rows), 16 cols each ----
  {
    const int r = tid >> 3, c = tid & 7;
    const float4* src = (const float4*)(X + (size_t)(row0 + r) * EDIM + c * 16);
    const unsigned xr = (unsigned)((r & 7) << 4);
    const float4 f0 = src[0], f1 = src[1], f2 = src[2], f3 = src[3];
    const uint4 v0 = make_uint4(pk_bf16(f0.x, f0.y), pk_bf16(f0.z, f0.w),
                                pk_bf16(f1.x, f1.y), pk_bf16(f1.z, f1.w));
    const uint4 v1 = make_uint4(pk_bf16(f2.x, f2.y), pk_bf16(f2.z, f2.w),
                                pk_bf16(f3.x, f3.y), pk_bf16(f3.z, f3.w));
    *(uint4*)((char*)xs + ((unsigned)(r * 256 + c * 32) ^ xr)) = v0;
    *(uint4*)((char*)xs + ((unsigned)(r * 256 + c * 32 + 16) ^ xr)) = v1;
  }
  __syncthreads();

  const int lane = tid & 63, wv = tid >> 6;
  const int lq = lane & 15, qd = lane >> 4;
  const int n0 = wv * 32;

  // ---- B-frags once per wave (two 16-col tiles) ----
  short8v b0[4], b1[4];
  #pragma unroll
  for (int kk = 0; kk < 4; ++kk) {
    const unsigned ad = (unsigned)((n0 + lq) * 256 + kk * 64 + qd * 16)
                      ^ (unsigned)((lq & 7) << 4);
    b0[kk] = *(const short8v*)((const char*)wlds + ad);
    b1[kk] = *(const short8v*)((const char*)wlds + ad + 4096);  // +16 rows
  }

  const int nA = n0 + lq, nB = nA + 16;
  const float bzA = bias[nA], bzB = bias[nB];
  const int b_ = row0 >> 11;

  #pragma unroll
  for (int rt = 0; rt < 2; ++rt) {
    const int rowt = row0 + rt * 16;
    short8v a[4];
    afrags(xs + rt * 2048, lq, qd, a);

    float4v D0 = {0.f, 0.f, 0.f, 0.f}, D1 = {0.f, 0.f, 0.f, 0.f};
    #pragma unroll
    for (int kk = 0; kk < 4; ++kk) {
      D0 = __builtin_amdgcn_mfma_f32_16x16x32_bf16(a[kk], b0[kk], D0, 0, 0, 0);
      D1 = __builtin_amdgcn_mfma_f32_16x16x32_bf16(a[kk], b1[kk], D1, 0, 0, 0);
    }

    if (MODE == 3) {
      float* of = (float*)out + (size_t)(rowt + qd * 4) * EDIM + nA;
      #pragma unroll
      for (int r = 0; r < 4; ++r) {
        of[r * EDIM]      = D0[r] + bzA;
        of[r * EDIM + 16] = D1[r] + bzB;
      }
      continue;
    }

    const int srel = rowt & (SEQ - 1);

    if (MODE == 2) {
      // Vt[bh][tg][d][si]: row-tile = one 16-s tile; si = qd*4 + r.
      const int tg = srel >> 4;
      unsigned short* oU = (unsigned short*)out;
      {
        const int bh = b_ * NHEAD + (nA >> 3), dv = nA & 7;
        uint2 p;
        p.x = pk_bf16(D0[0] + bzA, D0[1] + bzA);
        p.y = pk_bf16(D0[2] + bzA, D0[3] + bzA);
        *(uint2*)(oU + (size_t)bh * (SEQ * HDIM) + tg * 128 + dv * 16 + qd * 4) = p;
      }
      {
        const int bh = b_ * NHEAD + (nB >> 3), dv = nB & 7;
        uint2 p;
        p.x = pk_bf16(D1[0] + bzB, D1[1] + bzB);
        p.y = pk_bf16(D1[2] + bzB, D1[3] + bzB);
        *(uint2*)(oU + (size_t)bh * (SEQ * HDIM) + tg * 128 + dv * 16 + qd * 4) = p;
      }
      continue;
    }

    // MODE 0/1: bounce both 16x16 tiles through padded LDS ([16][20] u16),
    // then contiguous 256B uint4 stores (one [bh][s][8] row per lane).
    #pragma unroll
    for (int r = 0; r < 4; ++r) {
      float vA = D0[r] + bzA, vB = D1[r] + bzB;
      if (MODE == 0) { vA *= QNEG; vB *= QNEG; }
      const int m = qd * 4 + r;
      bnc[m * 20 + lq]       = (unsigned short)pk_bf16(vA, 0.f);
      bnc[320 + m * 20 + lq] = (unsigned short)pk_bf16(vB, 0.f);
    }
    __syncthreads();                              // LDS write->read order

    const int mm   = lane & 15;
    const int half = (lane >> 4) & 1;
    const int tile = lane >> 5;
    const unsigned short* sp = bnc + tile * 320 + mm * 20 + half * 8;
    const uint2 w0 = *(const uint2*)sp;
    const uint2 w1 = *(const uint2*)(sp + 4);
    const int bh = b_ * NHEAD + wv * 4 + tile * 2 + half;
    unsigned short* dp = (unsigned short*)out + ((size_t)bh * SEQ + srel + mm) * 8;
    *(uint4*)dp = make_uint4(w0.x, w0.y, w1.x, w1.y);
    __syncthreads();                              // bnc reuse guard (next rt)
  }
}

__global__ __launch_bounds__(256)
void qkv_kernel(const float* __restrict__ X,
                const float* __restrict__ Wq, const float* __restrict__ Wk,
                const float* __restrict__ Wv,
                const float* __restrict__ bq, const float* __restrict__ bk,
                const float* __restrict__ bv,
                unsigned* __restrict__ qb, unsigned* __restrict__ kb,
                unsigned* __restrict__ vb)
{
  __shared__ __align__(16) unsigned short wlds[16384];   // 32 KB
  __shared__ __align__(16) unsigned short xs[4096];      // 8 KB
  __shared__ __align__(16) unsigned short bnc[4 * 640];  // 5 KB
  const int tid = threadIdx.x;
  const int row0 = blockIdx.x * 32;
  unsigned short* myb = bnc + (tid >> 6) * 640;
  const int m = blockIdx.y;
  if (m == 0)      proj32<0>(X, Wq, bq, (void*)qb, row0, tid, wlds, xs, myb);
  else if (m == 1) proj32<1>(X, Wk, bk, (void*)kb, row0, tid, wlds, xs, myb);
  else             proj32<2>(X, Wv, bv, (void*)vb, row0, tid, wlds, xs, myb);
}

__global__ __launch_bounds__(256)
void oproj_kernel(const float* __restrict__ A, const float* __restrict__ Wo,
                  const float* __restrict__ bo, float* __restrict__ out)
{
  __shared__ __align__(16) unsigned short wlds[16384];   // 32 KB
  __shared__ __align__(16) unsigned short xs[4096];      // 8 KB
  proj32<3>(A, Wo, bo, (void*)out, blockIdx.x * 32, threadIdx.x, wlds, xs, nullptr);
}

// ---------------------------------------------------------------------------
// One 16q x 16k MFMA step.  REVERTED to the verified 4-rcp form (R10/42.4us):
// batched-rcp measured +9.6us (trans issue = 8cyc/op, but the batched chain
// adds ~50 VALU-cycles/step — attn is issue-saturated, every op counts).
// S^T = mfma_16x16x32_bf16(A=K-rows, B=Q-frag) -> C[key][q]. Sigmoid
// elementwise; C-register reinterpreted as A-operand of mfma_16x16x16 gives
// the UN-transposed P, so out[q][d] = mfma(A=P, B=V-frag, acc). V-frag col 8
// is forced to 1.0 so acc col 8 accumulates the denominator.
// ---------------------------------------------------------------------------
template<bool DIAG>
__device__ __forceinline__
float4v attn_step(short8v kf, short8v qf, short4v vf, float4v acc,
                  int laneq, int quad)
{
  const float4v z = {0.f, 0.f, 0.f, 0.f};
  float4v st = __builtin_amdgcn_mfma_f32_16x16x32_bf16(kf, qf, z, 0, 0, 0);
  unsigned rb[4];
  #pragma unroll
  for (int r = 0; r < 4; ++r) {
    float s = RCPF(1.f + EXP2F(st[r]));           // Q carries -scale*log2e
    if (DIAG) s = (4 * quad + r <= laneq) ? s : 0.f;  // exact: sigma(-1e9)==0
    rb[r] = __float_as_uint(s) + 0x8000u;         // round-half-up to bf16
  }
  U16x4 p;
  p.u.x = __builtin_amdgcn_perm(rb[1], rb[0], 0x07060302u);
  p.u.y = __builtin_amdgcn_perm(rb[3], rb[2], 0x07060302u);
  return MFMA_PV(p.s, vf, acc);                   // A = P[q][k], B = V[k][d]
}

// V-frag loader from tile-blocked Vt[bh][t][d][si]: ONE dwordx2 from a
// contiguous 256B tile block. lanes laneq==8 -> bf16 1.0 (denominator col).
__device__ __forceinline__
short4v load_vfrag(const unsigned short* __restrict__ Vtbh, int t,
                   int quad, int d, bool is8)
{
  const unsigned short* p = Vtbh + t * 128 + d * 16 + 4 * quad;
  const uint2 v = *(const uint2*)p;
  U16x4 vf;
  vf.u.x = is8 ? 0x3F803F80u : v.x;
  vf.u.y = is8 ? 0x3F803F80u : v.y;
  return vf.s;
}

// epilogue: den = acc col 8; normalize and store rows of tile T
__device__ __forceinline__
void epilogue(float4v acc, int T, int bh, int laneq, int quad,
              float* __restrict__ out)
{
  const int b_ = bh >> 4, h = bh & 15;
  const int pidx = (quad * 16 + 8) << 2;          // lane holding col 8
  #pragma unroll
  for (int r = 0; r < 4; ++r) {
    const float den = __int_as_float(
        __builtin_amdgcn_ds_bpermute(pidx, __float_as_int(acc[r])));
    const float val = acc[r] * RCPF(den);         // den > 0
    const int row = 16 * T + 4 * quad + r;
    if (laneq < 8)
      out[(size_t)(b_ * SEQ + row) * EDIM + h * HDIM + laneq] = val;
  }
}

// ---------------------------------------------------------------------------
// Causal sigmoid-attention v13: v11 schedule with w0's fused loop SPLIT into
// a dual loop [0,mL) and an H-only loop [mL,mH) — removes the per-iteration
// `if (t < mL)` compare/branch from w0's issue stream (attn is
// issue-saturated; every instruction counts). Math unchanged vs v11.
// blockIdx low 6 bits = bh -> XCD = bh%8 (L2 locality).
// ---------------------------------------------------------------------------
__global__ __launch_bounds__(128, 8)
void attn_kernel(const unsigned* __restrict__ Qb, const unsigned* __restrict__ Kb,
                 const unsigned* __restrict__ Vb, float* __restrict__ out)
{
  __shared__ float cmb[2][64][4];                 // 2 KB

  const int bh    = blockIdx.x & 63;
  const int g     = blockIdx.x >> 6;              // 0..63
  const int w     = threadIdx.x >> 6;
  const int lane  = threadIdx.x & 63;
  const int laneq = lane & 15;
  const int quad  = lane >> 4;
  const int L = g, H = 127 - g;
  const int mL = (L + 1) >> 1, mH = (H + 1) >> 1;
  const int d   = laneq & 7;
  const bool is8 = (laneq == 8);

  const uint4* Kg = (const uint4*)Kb + (size_t)bh * 2048;
  const uint4* Qg = (const uint4*)Qb + (size_t)bh * 2048;
  const unsigned short* Vtbh = (const unsigned short*)Vb + (size_t)bh * SEQ * HDIM;

  // Q B-frags: lanes<16 hold the 8-dim row in quad 0 (k=0..7); zero others
  U16x8 qfl, qfh;
  {
    const uint4 rl = Qg[16 * L + laneq];
    const uint4 rh = Qg[16 * H + laneq];
    qfl.u = (lane < 16) ? rl : make_uint4(0u, 0u, 0u, 0u);
    qfh.u = (lane < 16) ? rh : make_uint4(0u, 0u, 0u, 0u);
  }

  float4v accL = {0.f, 0.f, 0.f, 0.f};
  float4v accH = {0.f, 0.f, 0.f, 0.f};

  if (w == 0) {
    // dual loop [0,mL): L+H share k/v frags; then H-only [mL,mH). No diags.
    U16x8 kf; kf.u = Kg[laneq];
    short4v vf = load_vfrag(Vtbh, 0, quad, d, is8);
    int t = 0;
    #pragma unroll 2
    for (; t < mL; ++t) {
      U16x8 kn; kn.u = Kg[16 * (t + 1) + laneq];  // t+1 <= mL <= 32: in-bounds
      short4v vn = load_vfrag(Vtbh, t + 1, quad, d, is8);
      accL = attn_step<false>(kf.s, qfl.s, vf, accL, laneq, quad);
      accH = attn_step<false>(kf.s, qfh.s, vf, accH, laneq, quad);
      kf = kn; vf = vn;
    }
    #pragma unroll 2
    for (; t < mH; ++t) {
      U16x8 kn; kn.u = Kg[16 * (t + 1) + laneq];  // t+1 <= mH <= 64: in-bounds
      short4v vn = load_vfrag(Vtbh, t + 1, quad, d, is8);
      accH = attn_step<false>(kf.s, qfh.s, vf, accH, laneq, quad);
      kf = kn; vf = vn;
    }
  } else {
    // L segment: [mL, L], diag at L
    U16x8 kf; kf.u = Kg[16 * mL + laneq];
    short4v vf = load_vfrag(Vtbh, mL, quad, d, is8);
    #pragma unroll 2
    for (int t = mL; t < L; ++t) {
      U16x8 kn; kn.u = Kg[16 * (t + 1) + laneq];
      short4v vn = load_vfrag(Vtbh, t + 1, quad, d, is8);
      accL = attn_step<false>(kf.s, qfl.s, vf, accL, laneq, quad);
      kf = kn; vf = vn;
    }
    accL = attn_step<true>(kf.s, qfl.s, vf, accL, laneq, quad);
    // H segment: [mH, H], diag at H
    kf.u = Kg[16 * mH + laneq];
    vf = load_vfrag(Vtbh, mH, quad, d, is8);
    #pragma unroll 2
    for (int t = mH; t < H; ++t) {
      U16x8 kn; kn.u = Kg[16 * (t + 1) + laneq];  // t+1 <= H = 127: in-bounds
      short4v vn = load_vfrag(Vtbh, t + 1, quad, d, is8);
      accH = attn_step<false>(kf.s, qfh.s, vf, accH, laneq, quad);
      kf = kn; vf = vn;
    }
    accH = attn_step<true>(kf.s, qfh.s, vf, accH, laneq, quad);

    *(float4*)&cmb[0][lane][0] = make_float4(accL[0], accL[1], accL[2], accL[3]);
    *(float4*)&cmb[1][lane][0] = make_float4(accH[0], accH[1], accH[2], accH[3]);
  }
  __syncthreads();

  if (w == 0) {
    const float4 pL = *(const float4*)&cmb[0][lane][0];
    const float4 pH = *(const float4*)&cmb[1][lane][0];
    accL[0] += pL.x; accL[1] += pL.y; accL[2] += pL.z; accL[3] += pL.w;
    accH[0] += pH.x; accH[1] += pH.y; accH[2] += pH.z; accH[3] += pH.w;
    epilogue(accL, L, bh, laneq, quad, out);
    epilogue(accH, H, bh, laneq, quad, out);
  }
}

// ---------------------------------------------------------------------------
extern "C" void kernel_launch(void* const* d_in, const int* in_sizes, int n_in,
                              void* d_out, int out_size, void* d_ws, size_t ws_size,
                              hipStream_t stream)
{
  const float* x  = (const float*)d_in[0];
  const float* Wq = (const float*)d_in[1];
  const float* bq = (const float*)d_in[2];
  const float* Wk = (const float*)d_in[3];
  const float* bk = (const float*)d_in[4];
  const float* Wv = (const float*)d_in[5];
  const float* bv = (const float*)d_in[6];
  const float* Wo = (const float*)d_in[7];
  const float* bo = (const float*)d_in[8];

  float* ws = (float*)d_ws;
  // layout: (64K floats reserved) | attn 1048576 f | Qb, Kb, Vt 524288 dw each
  float*    attn = ws + 65536;
  unsigned* Qb   = (unsigned*)(ws + 65536 + 1048576);
  unsigned* Kb   = Qb + (size_t)524288;
  unsigned* Vb   = Kb + (size_t)524288;

  qkv_kernel<<<dim3(NROW / 32, 3), 256, 0, stream>>>(x, Wq, Wk, Wv, bq, bk, bv,
                                                     Qb, Kb, Vb);
  attn_kernel<<<dim3(4096), 128, 0, stream>>>(Qb, Kb, Vb, attn);
  oproj_kernel<<<dim3(NROW / 32), 256, 0, stream>>>(attn, Wo, bo, (float*)d_out);
}